// Round 14
// baseline (31.441 us; speedup 1.0000x reference)
//
#include <hip/hip_runtime.h>
#include <stdint.h>

constexpr int Dz = 96, Hy = 160, Wx = 160;
constexpr int NVOX = Dz * Hy * Wx;

// Wave-autonomous tile: 32d x 8w x 2h per WAVE; 2 waves per 128-thread block.
// Stage-1 footprint per wave: 6 z-rows x 3 y-rows x 56-dword aligned x-pitch.
constexpr int ZW = 6, YW = 3, XP = 56;          // LDS plane: [6][3][56] dwords
constexpr int ROWS = ZW * YW;                   // 18 (z,y) rows
constexpr int NCHUNK = ROWS * 14;               // 252 16B chunks per plane
constexpr int UI = 4;                           // width-16 issues/lane/plane
constexpr int WBUF = UI * 64 * 4;               // 1024 dwords per wave buffer

typedef __attribute__((address_space(3))) float lds_f;
typedef __attribute__((address_space(1))) const void gbl_v;

#define WAIT_VM(N)  do { asm volatile("s_waitcnt vmcnt(" #N ")" ::: "memory"); \
                         __builtin_amdgcn_sched_barrier(0); } while (0)
#define WAIT_LGKM() do { asm volatile("s_waitcnt lgkmcnt(0)" ::: "memory"); \
                         __builtin_amdgcn_sched_barrier(0); } while (0)

__global__ __launch_bounds__(128) void st_fused_kernel(
    const float* __restrict__ src,
    const float* __restrict__ flows,
    const float* __restrict__ rfp,
    float* __restrict__ out)
{
    __shared__ float raw[2][2][WBUF];   // 16384 B: per-wave private double buffers
    const int t = threadIdx.x;
    const int v = t >> 6;               // wave id 0..1
    const int lane = t & 63;

    // XCD-aware bijective swizzle (2400 = 8 x 300), then wave-linear tiling
    const int bid = blockIdx.x;
    const int swz = (bid & 7) * 300 + (bid >> 3);
    const int wid = swz * 2 + v;        // 0..4799
    const int wt = wid % 20;            // w-tile (8 w each)
    const int rest = wid / 20;
    const int dt = rest % 3;            // d-tile (32 d each)
    const int hp = rest / 3;            // h-pair 0..79
    const int w0w = wt * 8, d0 = dt * 32, h0 = hp * 2;
    const float rf = *rfp;

    const int Z0w = (19 * w0w) >> 5;
    const int X0 = 53 * dt;             // (53*d0)/32 exact
    const int X0a = X0 & ~3;            // 16B-aligned x origin
    const int YB = (159 * h0) / 160;

    // ---- 4 live chunk addresses (16B each), advanced by plane stride ----
    const char* ap[UI];
    {
        const char* fb = (const char*)flows + ((size_t)YB * Wx + X0a) * 4;
#pragma unroll
        for (int u = 0; u < UI; ++u) {
            int c = u * 64 + lane;
            if (c >= NCHUNK) c = NCHUNK - 1;     // tail dups (LDS junk, never read)
            int row = c / 14, ch = c - row * 14;
            int zr = row / 3, yr = row - zr * 3;
            ap[u] = fb + ((size_t)((Z0w + zr) * Hy + yr) * Wx) * 4 + ch * 16;
        }
    }

    auto issue_loads = [&](int buf) {
        lds_f* lb = (lds_f*)&raw[v][buf][0];     // wave-uniform base; HW adds lane*16B
#pragma unroll
        for (int u = 0; u < UI; ++u)
            __builtin_amdgcn_global_load_lds((gbl_v*)ap[u], lb + u * 256, 16, 0, 0);
#pragma unroll
        for (int u = 0; u < UI; ++u) ap[u] += (size_t)NVOX * 4;
    };

    // ---- compute mapping: lanes vary d (stage-2 x axis = stride 1) ----
    const int dl = lane & 31;
    const int half = lane >> 5;         // picks w quartet
    const int d = d0 + dl;

    const float xf = (float)(53 * d) * (1.0f / 32.0f);
    const int   x0i = (int)xf;
    const float fx  = xf - (float)x0i;
    const int   xx  = x0i - X0a;        // 0..54
    const float wxa = 1.0f - fx, wxb = fx;

    // ---- z-row factorization: per half, all 4 k's pairs live in 4 consecutive rows.
    // rowoff[r] = clamped row byte base; wkz[r][k] = z-weight of row r for output k.
    int rowoff[4];
    float wkz[4][4];
    {
        int zzk[4]; float wz0k[4], wz1k[4];
#pragma unroll
        for (int k = 0; k < 4; ++k) {
            const int w = w0w + 4 * half + k;
            const float zf = (float)(19 * w) * (1.0f / 32.0f);
            const int z0i = (int)zf;
            const float fz = zf - (float)z0i;
            zzk[k] = z0i - Z0w;         // 0..4, nondecreasing in k
            wz0k[k] = 1.0f - fz; wz1k[k] = fz;
        }
        const int zz0 = zzk[0];
#pragma unroll
        for (int r = 0; r < 4; ++r) {
            rowoff[r] = min(zz0 + r, ZW - 1) * (YW * XP);
#pragma unroll
            for (int k = 0; k < 4; ++k) {
                const int rel = zzk[k] - zz0;            // 0..2
                wkz[r][k] = (rel == r) ? wz0k[k] : ((rel == r - 1) ? wz1k[k] : 0.0f);
            }
        }
    }

    float wyr[2][3];
#pragma unroll
    for (int j = 0; j < 2; ++j) {
        const int h = h0 + j;
        const float yf = (float)h * (159.0f / 160.0f);
        const int y0i = (int)yf;
        const float fy = yf - (float)y0i;
        const int yrel = y0i - YB;      // 0 or 1
        const float a = 1.0f - fy, b = fy;
        wyr[j][0] = (yrel == 0) ? a : 0.0f;
        wyr[j][1] = (yrel == 0) ? b : a;
        wyr[j][2] = (yrel == 0) ? 0.0f : b;
    }

    // 12 ds_read_b64/plane (was 24): one x-interp per distinct row, then the
    // sparse wkz matrix scatters row values into the 4 k-accumulators.
    auto compute = [&](const float* lb, float (&acc)[4][2]) {
#pragma unroll
        for (int yy = 0; yy < 3; ++yy) {
            float zv0 = 0.f, zv1 = 0.f, zv2 = 0.f, zv3 = 0.f;
#pragma unroll
            for (int r = 0; r < 4; ++r) {
                const float* p = lb + rowoff[r] + yy * XP + xx;
                const float xv = wxa * p[0] + wxb * p[1];
                zv0 += wkz[r][0] * xv;
                zv1 += wkz[r][1] * xv;
                zv2 += wkz[r][2] * xv;
                zv3 += wkz[r][3] * xv;
            }
            acc[0][0] += wyr[0][yy] * zv0; acc[0][1] += wyr[1][yy] * zv0;
            acc[1][0] += wyr[0][yy] * zv1; acc[1][1] += wyr[1][yy] * zv1;
            acc[2][0] += wyr[0][yy] * zv2; acc[2][1] += wyr[1][yy] * zv2;
            acc[3][0] += wyr[0][yy] * zv3; acc[3][1] += wyr[1][yy] * zv3;
        }
    };

    float accA[4][2], accB[4][2], accC[4][2];
#pragma unroll
    for (int k = 0; k < 4; ++k)
#pragma unroll
        for (int j = 0; j < 2; ++j) { accA[k][j] = 0.f; accB[k][j] = 0.f; accC[k][j] = 0.f; }

    // ---- barrier-free per-wave pipeline: dbuf, counted vmcnt ----
    issue_loads(0);      // plane 0
    issue_loads(1);      // plane 1
    int cur = 0;

#pragma unroll 1
    for (int i = 0; i < 2; ++i) {       // planes 0..5
        WAIT_VM(4);
        compute(&raw[v][cur][0], accA);
        issue_loads(cur); cur ^= 1;

        WAIT_VM(4);
        compute(&raw[v][cur][0], accB);
        issue_loads(cur); cur ^= 1;

        WAIT_VM(4);
        compute(&raw[v][cur][0], accC);
        issue_loads(cur); cur ^= 1;
    }
    WAIT_VM(4);                         // plane 6
    compute(&raw[v][cur][0], accA);
    issue_loads(cur); cur ^= 1;         // plane 8
    WAIT_VM(4);                         // plane 7
    compute(&raw[v][cur][0], accB);
    cur ^= 1;
    WAIT_VM(0);                         // plane 8
    compute(&raw[v][cur][0], accC);

    // ---- stage 2: row-paired src sampling (zeros mode); results go straight to
    // wave-private transpose LDS (in-order LDS pipe: writes follow plane-8 reads) ----
    float* tr = &raw[v][0][0];          // 2 tiles of [32][9] dwords (576 <= 2048)
#pragma unroll
    for (int j = 0; j < 2; ++j) {
        const int h = h0 + j;
#pragma unroll
        for (int k = 0; k < 4; ++k) {
            const int w = w0w + 4 * half + k;
            const float f0 = (float)d + accA[k][j] * rf;   // -> x axis of src
            const float f1 = (float)h + accB[k][j] * rf;   // -> y axis
            const float f2 = (float)w + accC[k][j] * rf;   // -> z axis

            const float xs = f0 * (159.0f / 95.0f);
            const float ys = f1;
            const float zs = f2 * (95.0f / 159.0f);

            const float xf0 = floorf(xs), yf0 = floorf(ys), zf0 = floorf(zs);
            const float gx = xs - xf0, gy = ys - yf0, gz = zs - zf0;
            const int xi0 = (int)xf0, yi0 = (int)yf0, zi0 = (int)zf0;

            // x pair: one clamped base, select handles borders exactly
            const int xc = min(max(xi0, 0), Wx - 2);
            const bool sx0 = (xi0 == xc);
            const float wx0m = ((unsigned)xi0 < (unsigned)Wx) ? (1.0f - gx) : 0.0f;
            const float wx1m = ((unsigned)(xi0 + 1) < (unsigned)Wx) ? gx : 0.0f;

            const int yc0 = min(max(yi0, 0), Hy - 1);
            const int yc1 = min(max(yi0 + 1, 0), Hy - 1);
            const int zc0 = min(max(zi0, 0), Dz - 1);
            const int zc1 = min(max(zi0 + 1, 0), Dz - 1);
            const float wy0m = ((unsigned)yi0 < (unsigned)Hy) ? (1.0f - gy) : 0.0f;
            const float wy1m = ((unsigned)(yi0 + 1) < (unsigned)Hy) ? gy : 0.0f;
            const float wz0m = ((unsigned)zi0 < (unsigned)Dz) ? (1.0f - gz) : 0.0f;
            const float wz1m = ((unsigned)(zi0 + 1) < (unsigned)Dz) ? gz : 0.0f;

            const float w00 = wz0m * wy0m, w01 = wz0m * wy1m;
            const float w10 = wz1m * wy0m, w11 = wz1m * wy1m;

            float r = 0.0f;
            auto rowadd = [&](int zc, int yc, float wt) {
                const float* p = src + ((size_t)zc * Hy + yc) * Wx + xc;
                const float va = p[0], vb = p[1];
                const float s0 = sx0 ? va : vb;   // value at xi0 (xi0==159 -> vb)
                const float s1 = sx0 ? vb : va;   // value at xi1 (xi0==-1 -> va)
                r += wt * (wx0m * s0 + wx1m * s1);
            };
            rowadd(zc0, yc0, w00);
            rowadd(zc0, yc1, w01);
            rowadd(zc1, yc0, w10);
            rowadd(zc1, yc1, w11);

            tr[j * 288 + dl * 9 + 4 * half + k] = r;
        }
    }
    WAIT_LGKM();

    const int rrow = lane >> 3;         // 0..7
    const int rcol = lane & 7;          // 0..7
#pragma unroll
    for (int j = 0; j < 2; ++j)
#pragma unroll
        for (int m = 0; m < 4; ++m) {
            const int dr = m * 8 + rrow;
            out[((size_t)(d0 + dr) * Hy + (h0 + j)) * Wx + (w0w + rcol)] =
                tr[j * 288 + dr * 9 + rcol];
        }
}

extern "C" void kernel_launch(void* const* d_in, const int* in_sizes, int n_in,
                              void* d_out, int out_size, void* d_ws, size_t ws_size,
                              hipStream_t stream) {
    const float* src   = (const float*)d_in[0];
    const float* flows = (const float*)d_in[1];
    const float* rfp   = (const float*)d_in[2];
    float* out = (float*)d_out;

    st_fused_kernel<<<dim3(2400), 128, 0, stream>>>(src, flows, rfp, out);
}

// Round 15
// 30.200 us; speedup vs baseline: 1.0411x; 1.0411x over previous
//
#include <hip/hip_runtime.h>
#include <stdint.h>

constexpr int Dz = 96, Hy = 160, Wx = 160;
constexpr int NVOX = Dz * Hy * Wx;

// Wave-autonomous tile: 32d x 8w x 2h per WAVE; 2 waves per 128-thread block.
// Stage-1 footprint per wave: 6 z-rows x 3 y-rows x 56-dword aligned x-pitch.
constexpr int ZW = 6, YW = 3, XP = 56;          // LDS plane: [6][3][56] dwords
constexpr int ROWS = ZW * YW;                   // 18 (z,y) rows
constexpr int NCHUNK = ROWS * 14;               // 252 16B chunks per plane
constexpr int UI = 4;                           // chunk rounds (4*64 >= 252)
constexpr int WBUF = UI * 64 * 4;               // 1024 dwords per wave buffer

#define WAIT_LGKM() do { asm volatile("s_waitcnt lgkmcnt(0)" ::: "memory"); \
                         __builtin_amdgcn_sched_barrier(0); } while (0)
#define FENCE() __builtin_amdgcn_sched_barrier(0)

__global__ __launch_bounds__(128) void st_fused_kernel(
    const float* __restrict__ src,
    const float* __restrict__ flows,
    const float* __restrict__ rfp,
    float* __restrict__ out)
{
    __shared__ float raw[2][WBUF];      // 8 KB: one summed-plane buffer per wave
    const int t = threadIdx.x;
    const int v = t >> 6;               // wave id 0..1
    const int lane = t & 63;

    // XCD-aware bijective swizzle (2400 = 8 x 300), then wave-linear tiling
    const int bid = blockIdx.x;
    const int swz = (bid & 7) * 300 + (bid >> 3);
    const int wid = swz * 2 + v;        // 0..4799
    const int wt = wid % 20;            // w-tile (8 w each)
    const int rest = wid / 20;
    const int dt = rest % 3;            // d-tile (32 d each)
    const int hp = rest / 3;            // h-pair 0..79
    const int w0w = wt * 8, d0 = dt * 32, h0 = hp * 2;
    const float rf = *rfp;

    const int Z0w = (19 * w0w) >> 5;
    const int X0 = 53 * dt;             // (53*d0)/32 exact
    const int X0a = X0 & ~3;            // 16B-aligned x origin
    const int YB = (159 * h0) / 160;

    // ---- 4 live chunk addresses (16B each), advanced by channel (plane) stride ----
    const char* ap[UI];
    {
        const char* fb = (const char*)flows + ((size_t)YB * Wx + X0a) * 4;
#pragma unroll
        for (int u = 0; u < UI; ++u) {
            int c = u * 64 + lane;
            if (c >= NCHUNK) c = NCHUNK - 1;     // tail dups (LDS junk, never read)
            int row = c / 14, ch = c - row * 14;
            int zr = row / 3, yr = row - zr * 3;
            ap[u] = fb + ((size_t)((Z0w + zr) * Hy + yr) * Wx) * 4 + ch * 16;
        }
    }

    // ---- channel staging: load same channel of all 3 flow stages, sum, commit ----
    // Linearity: sum-before-interp == interp-before-sum (same sample coords for all).
    float4 nxt[3][UI];                  // 48 VGPR in flight
    auto issue_ch = [&]() {
#pragma unroll
        for (int i = 0; i < 3; ++i)
#pragma unroll
            for (int u = 0; u < UI; ++u)
                nxt[i][u] = *(const float4*)(ap[u] + (size_t)i * (3u * NVOX * 4u));
#pragma unroll
        for (int u = 0; u < UI; ++u) ap[u] += (size_t)NVOX * 4;   // next channel
    };
    float* const lb = &raw[v][0];
    auto commit_ch = [&]() {
        float4* lb4 = (float4*)lb;
#pragma unroll
        for (int u = 0; u < UI; ++u) {
            float4 s;
            s.x = (nxt[0][u].x + nxt[1][u].x) + nxt[2][u].x;
            s.y = (nxt[0][u].y + nxt[1][u].y) + nxt[2][u].y;
            s.z = (nxt[0][u].z + nxt[1][u].z) + nxt[2][u].z;
            s.w = (nxt[0][u].w + nxt[1][u].w) + nxt[2][u].w;
            lb4[u * 64 + lane] = s;
        }
    };

    // ---- compute mapping: lanes vary d (stage-2 x axis = stride 1) ----
    const int dl = lane & 31;
    const int half = lane >> 5;         // picks w quartet
    const int d = d0 + dl;

    const float xf = (float)(53 * d) * (1.0f / 32.0f);
    const int   x0i = (int)xf;
    const float fx  = xf - (float)x0i;
    const int   xx  = x0i - X0a;        // 0..54
    const float wxa = 1.0f - fx, wxb = fx;

    // z-row factorization: all 4 k's (zz,zz+1) pairs live in 4 consecutive rows.
    int rowoff[4];
    float wkz[4][4];
    {
        int zzk[4]; float wz0k[4], wz1k[4];
#pragma unroll
        for (int k = 0; k < 4; ++k) {
            const int w = w0w + 4 * half + k;
            const float zf = (float)(19 * w) * (1.0f / 32.0f);
            const int z0i = (int)zf;
            const float fz = zf - (float)z0i;
            zzk[k] = z0i - Z0w;         // 0..4, nondecreasing in k
            wz0k[k] = 1.0f - fz; wz1k[k] = fz;
        }
        const int zz0 = zzk[0];
#pragma unroll
        for (int r = 0; r < 4; ++r) {
            rowoff[r] = min(zz0 + r, ZW - 1) * (YW * XP);
#pragma unroll
            for (int k = 0; k < 4; ++k) {
                const int rel = zzk[k] - zz0;            // 0..2
                wkz[r][k] = (rel == r) ? wz0k[k] : ((rel == r - 1) ? wz1k[k] : 0.0f);
            }
        }
    }

    float wyr[2][3];
#pragma unroll
    for (int j = 0; j < 2; ++j) {
        const int h = h0 + j;
        const float yf = (float)h * (159.0f / 160.0f);
        const int y0i = (int)yf;
        const float fy = yf - (float)y0i;
        const int yrel = y0i - YB;      // 0 or 1
        const float a = 1.0f - fy, b = fy;
        wyr[j][0] = (yrel == 0) ? a : 0.0f;
        wyr[j][1] = (yrel == 0) ? b : a;
        wyr[j][2] = (yrel == 0) ? 0.0f : b;
    }

    // 12 row-pair LDS reads per channel (one x-interp per distinct row);
    // sparse wkz scatters rows into the 4 k outputs.
    auto compute = [&](float (&acc)[4][2]) {
#pragma unroll
        for (int yy = 0; yy < 3; ++yy) {
            float zv0 = 0.f, zv1 = 0.f, zv2 = 0.f, zv3 = 0.f;
#pragma unroll
            for (int r = 0; r < 4; ++r) {
                const float* p = lb + rowoff[r] + yy * XP + xx;
                const float xv = wxa * p[0] + wxb * p[1];
                zv0 += wkz[r][0] * xv;
                zv1 += wkz[r][1] * xv;
                zv2 += wkz[r][2] * xv;
                zv3 += wkz[r][3] * xv;
            }
            acc[0][0] += wyr[0][yy] * zv0; acc[0][1] += wyr[1][yy] * zv0;
            acc[1][0] += wyr[0][yy] * zv1; acc[1][1] += wyr[1][yy] * zv1;
            acc[2][0] += wyr[0][yy] * zv2; acc[2][1] += wyr[1][yy] * zv2;
            acc[3][0] += wyr[0][yy] * zv3; acc[3][1] += wyr[1][yy] * zv3;
        }
    };

    float accA[4][2], accB[4][2], accC[4][2];
#pragma unroll
    for (int k = 0; k < 4; ++k)
#pragma unroll
        for (int j = 0; j < 2; ++j) { accA[k][j] = 0.f; accB[k][j] = 0.f; accC[k][j] = 0.f; }

    // ---- 3-phase pipeline: loads of ch c+1 in flight under compute of ch c.
    // Same-wave LDS ordering makes the single buffer safe (write after prior read).
    issue_ch();            // ch0
    commit_ch();
    issue_ch();            // ch1
    compute(accA);         // ch0; ch1 loads in flight
    FENCE();
    commit_ch();
    issue_ch();            // ch2
    compute(accB);         // ch1; ch2 loads in flight
    FENCE();
    commit_ch();
    compute(accC);         // ch2

    // ---- stage 2: row-paired src sampling (zeros mode); results straight to
    // wave-private transpose LDS (same-wave ordering) ----
    float* tr = &raw[v][0];             // 2 tiles of [32][9] dwords (576 <= 1024)
#pragma unroll
    for (int j = 0; j < 2; ++j) {
        const int h = h0 + j;
#pragma unroll
        for (int k = 0; k < 4; ++k) {
            const int w = w0w + 4 * half + k;
            const float f0 = (float)d + accA[k][j] * rf;   // -> x axis of src
            const float f1 = (float)h + accB[k][j] * rf;   // -> y axis
            const float f2 = (float)w + accC[k][j] * rf;   // -> z axis

            const float xs = f0 * (159.0f / 95.0f);
            const float ys = f1;
            const float zs = f2 * (95.0f / 159.0f);

            const float xf0 = floorf(xs), yf0 = floorf(ys), zf0 = floorf(zs);
            const float gx = xs - xf0, gy = ys - yf0, gz = zs - zf0;
            const int xi0 = (int)xf0, yi0 = (int)yf0, zi0 = (int)zf0;

            const int xc = min(max(xi0, 0), Wx - 2);
            const bool sx0 = (xi0 == xc);
            const float wx0m = ((unsigned)xi0 < (unsigned)Wx) ? (1.0f - gx) : 0.0f;
            const float wx1m = ((unsigned)(xi0 + 1) < (unsigned)Wx) ? gx : 0.0f;

            const int yc0 = min(max(yi0, 0), Hy - 1);
            const int yc1 = min(max(yi0 + 1, 0), Hy - 1);
            const int zc0 = min(max(zi0, 0), Dz - 1);
            const int zc1 = min(max(zi0 + 1, 0), Dz - 1);
            const float wy0m = ((unsigned)yi0 < (unsigned)Hy) ? (1.0f - gy) : 0.0f;
            const float wy1m = ((unsigned)(yi0 + 1) < (unsigned)Hy) ? gy : 0.0f;
            const float wz0m = ((unsigned)zi0 < (unsigned)Dz) ? (1.0f - gz) : 0.0f;
            const float wz1m = ((unsigned)(zi0 + 1) < (unsigned)Dz) ? gz : 0.0f;

            const float w00 = wz0m * wy0m, w01 = wz0m * wy1m;
            const float w10 = wz1m * wy0m, w11 = wz1m * wy1m;

            float r = 0.0f;
            auto rowadd = [&](int zc, int yc, float wt) {
                const float* p = src + ((size_t)zc * Hy + yc) * Wx + xc;
                const float va = p[0], vb = p[1];
                const float s0 = sx0 ? va : vb;   // value at xi0 (xi0==159 -> vb)
                const float s1 = sx0 ? vb : va;   // value at xi1 (xi0==-1 -> va)
                r += wt * (wx0m * s0 + wx1m * s1);
            };
            rowadd(zc0, yc0, w00);
            rowadd(zc0, yc1, w01);
            rowadd(zc1, yc0, w10);
            rowadd(zc1, yc1, w11);

            tr[j * 288 + dl * 9 + 4 * half + k] = r;
        }
    }
    WAIT_LGKM();

    const int rrow = lane >> 3;         // 0..7
    const int rcol = lane & 7;          // 0..7
#pragma unroll
    for (int j = 0; j < 2; ++j)
#pragma unroll
        for (int m = 0; m < 4; ++m) {
            const int dr = m * 8 + rrow;
            out[((size_t)(d0 + dr) * Hy + (h0 + j)) * Wx + (w0w + rcol)] =
                tr[j * 288 + dr * 9 + rcol];
        }
}

extern "C" void kernel_launch(void* const* d_in, const int* in_sizes, int n_in,
                              void* d_out, int out_size, void* d_ws, size_t ws_size,
                              hipStream_t stream) {
    const float* src   = (const float*)d_in[0];
    const float* flows = (const float*)d_in[1];
    const float* rfp   = (const float*)d_in[2];
    float* out = (float*)d_out;

    st_fused_kernel<<<dim3(2400), 128, 0, stream>>>(src, flows, rfp, out);
}